// Round 1
// baseline (639.241 us; speedup 1.0000x reference)
//
#include <hip/hip_runtime.h>

#define D_MODEL   128
#define NUM_HEADS 8
#define DK        16
#define NUM_NODES 207
#define SEQ_LEN   12
#define BATCH     4
#define L_TOTAL   (SEQ_LEN * NUM_NODES)   // 2484
#define BL        (BATCH * L_TOTAL)       // 9936
#define TK        414                     // 2484 = 6*414; 414 = 2*207 (nk phase restarts each tile)

// msmT[nk][nq] = 0.25 * sigmoid(temporal) * sigmoid(spatial[nq][nk])
// Transposed so that the attention inner loop (fixed nk, per-thread consecutive nq)
// loads are coalesced. 0.25 = 1/sqrt(dk) folded in.
__global__ void mask_prep_kernel(const float* __restrict__ tmask,
                                 const float* __restrict__ smask,
                                 float* __restrict__ msmT) {
    int idx = blockIdx.x * 256 + threadIdx.x;
    if (idx >= NUM_NODES * NUM_NODES) return;
    int nk = idx / NUM_NODES;
    int nq = idx - nk * NUM_NODES;
    float tm = 1.0f / (1.0f + __expf(-tmask[0]));
    float sm = 1.0f / (1.0f + __expf(-smask[nq * NUM_NODES + nk]));
    msmT[idx] = 0.25f * tm * sm;
}

// Q/K/V projection: 16 rows per block, 128 threads (thread = output column).
// Output layout: [b*H + h][l][dk]  (head-major for attention).
__global__ __launch_bounds__(128) void qkv_proj_kernel(
    const float* __restrict__ x,
    const float* __restrict__ Wq, const float* __restrict__ bq,
    const float* __restrict__ Wk, const float* __restrict__ bk,
    const float* __restrict__ Wv, const float* __restrict__ bv,
    float* __restrict__ Q, float* __restrict__ K, float* __restrict__ V)
{
    __shared__ float xs[16][D_MODEL];
    const int t = threadIdx.x;
    const int row0 = blockIdx.x * 16;
    #pragma unroll
    for (int r = 0; r < 16; ++r)
        xs[r][t] = x[(size_t)(row0 + r) * D_MODEL + t];
    __syncthreads();

    float aq[16], ak[16], av[16];
    #pragma unroll
    for (int r = 0; r < 16; ++r) { aq[r] = 0.f; ak[r] = 0.f; av[r] = 0.f; }

    for (int i = 0; i < D_MODEL; ++i) {
        float wq = Wq[i * D_MODEL + t];
        float wk = Wk[i * D_MODEL + t];
        float wv = Wv[i * D_MODEL + t];
        #pragma unroll
        for (int r = 0; r < 16; ++r) {
            float xv = xs[r][i];          // uniform address -> LDS broadcast
            aq[r] += xv * wq;
            ak[r] += xv * wk;
            av[r] += xv * wv;
        }
    }

    const float bqv = bq[t], bkv = bk[t], bvv = bv[t];
    const int h = t >> 4, d = t & 15;
    #pragma unroll
    for (int r = 0; r < 16; ++r) {
        int row = row0 + r;               // row = b*L + l
        int b = row / L_TOTAL;
        int l = row - b * L_TOTAL;
        size_t o = ((size_t)(b * NUM_HEADS + h) * L_TOTAL + l) * DK + d;
        Q[o] = aq[r] + bqv;
        K[o] = ak[r] + bkv;
        V[o] = av[r] + bvv;
    }
}

// Flash-style attention: 1 thread per query row, online softmax.
// Block: 256 threads; grid: (ceil(L/256), B*H).
__global__ __launch_bounds__(256) void attn_kernel(
    const float* __restrict__ Q, const float* __restrict__ K,
    const float* __restrict__ V, const float* __restrict__ msmT,
    float* __restrict__ ctxout)
{
    __shared__ float Ks[TK * DK];
    __shared__ float Vs[TK * DK];

    const int t  = threadIdx.x;
    const int bh = blockIdx.y;                    // b*8 + h
    const int l  = blockIdx.x * 256 + t;
    const bool valid = (l < L_TOTAL);
    const int ll = valid ? l : 0;

    float q[DK];
    {
        const float* qp = Q + ((size_t)bh * L_TOTAL + ll) * DK;
        #pragma unroll
        for (int d = 0; d < DK; ++d) q[d] = qp[d];
    }
    const int nq = ll % NUM_NODES;

    float m = -1e30f, ssum = 0.f;
    float ctx[DK];
    #pragma unroll
    for (int d = 0; d < DK; ++d) ctx[d] = 0.f;

    const float* Kbase = K + (size_t)bh * L_TOTAL * DK;
    const float* Vbase = V + (size_t)bh * L_TOTAL * DK;

    for (int kt = 0; kt < L_TOTAL; kt += TK) {
        // cooperative stage of K/V tile (414 rows x 16 floats each)
        const float4* kp4 = (const float4*)(Kbase + (size_t)kt * DK);
        const float4* vp4 = (const float4*)(Vbase + (size_t)kt * DK);
        for (int j = t; j < TK * DK / 4; j += 256) {
            ((float4*)Ks)[j] = kp4[j];
            ((float4*)Vs)[j] = vp4[j];
        }
        __syncthreads();

        if (valid) {
            int nk = 0;   // kt is a multiple of 414 = 2*207 -> phase restarts at 0
            for (int kk = 0; kk < TK; ++kk) {
                const float* krow = Ks + kk * DK;
                float kv[DK];
                *(float4*)&kv[0]  = *(const float4*)(krow + 0);
                *(float4*)&kv[4]  = *(const float4*)(krow + 4);
                *(float4*)&kv[8]  = *(const float4*)(krow + 8);
                *(float4*)&kv[12] = *(const float4*)(krow + 12);

                float dot = 0.f;
                #pragma unroll
                for (int d = 0; d < DK; ++d) dot += q[d] * kv[d];

                float sc = dot * msmT[nk * NUM_NODES + nq];  // coalesced across lanes

                if (sc > m) {                 // rare after warm-up
                    float c = __expf(m - sc);
                    ssum *= c;
                    #pragma unroll
                    for (int d = 0; d < DK; ++d) ctx[d] *= c;
                    m = sc;
                }
                float p = __expf(sc - m);
                ssum += p;

                const float* vrow = Vs + kk * DK;
                float vv[DK];
                *(float4*)&vv[0]  = *(const float4*)(vrow + 0);
                *(float4*)&vv[4]  = *(const float4*)(vrow + 4);
                *(float4*)&vv[8]  = *(const float4*)(vrow + 8);
                *(float4*)&vv[12] = *(const float4*)(vrow + 12);
                #pragma unroll
                for (int d = 0; d < DK; ++d) ctx[d] += p * vv[d];

                nk = (nk + 1 == NUM_NODES) ? 0 : nk + 1;
            }
        }
        __syncthreads();
    }

    if (valid) {
        float inv = 1.0f / ssum;
        int b = bh >> 3, h = bh & 7;
        float* op = ctxout + ((size_t)b * L_TOTAL + l) * D_MODEL + h * DK;
        #pragma unroll
        for (int d = 0; d < DK; ++d) op[d] = ctx[d] * inv;
    }
}

// Output projection: context (9936x128) @ Wo + bo -> out
__global__ __launch_bounds__(128) void out_proj_kernel(
    const float* __restrict__ ctxin,
    const float* __restrict__ Wo, const float* __restrict__ bo,
    float* __restrict__ out)
{
    __shared__ float xs[16][D_MODEL];
    const int t = threadIdx.x;
    const int row0 = blockIdx.x * 16;
    #pragma unroll
    for (int r = 0; r < 16; ++r)
        xs[r][t] = ctxin[(size_t)(row0 + r) * D_MODEL + t];
    __syncthreads();

    float acc[16];
    #pragma unroll
    for (int r = 0; r < 16; ++r) acc[r] = 0.f;

    for (int i = 0; i < D_MODEL; ++i) {
        float w = Wo[i * D_MODEL + t];
        #pragma unroll
        for (int r = 0; r < 16; ++r) acc[r] += xs[r][i] * w;
    }

    float bv = bo[t];
    #pragma unroll
    for (int r = 0; r < 16; ++r)
        out[(size_t)(row0 + r) * D_MODEL + t] = acc[r] + bv;
}

extern "C" void kernel_launch(void* const* d_in, const int* in_sizes, int n_in,
                              void* d_out, int out_size, void* d_ws, size_t ws_size,
                              hipStream_t stream) {
    const float* x     = (const float*)d_in[0];
    const float* Wq    = (const float*)d_in[1];
    const float* bq    = (const float*)d_in[2];
    const float* Wk    = (const float*)d_in[3];
    const float* bk    = (const float*)d_in[4];
    const float* Wv    = (const float*)d_in[5];
    const float* bv    = (const float*)d_in[6];
    const float* Wo    = (const float*)d_in[7];
    const float* bo    = (const float*)d_in[8];
    const float* tmask = (const float*)d_in[9];
    const float* smask = (const float*)d_in[10];
    float* out = (float*)d_out;

    // workspace layout (total ~20.6 MB)
    char* ws = (char*)d_ws;
    size_t o = 0;
    float* msmT = (float*)(ws + o); o += ((size_t)NUM_NODES * NUM_NODES * 4 + 255) & ~(size_t)255;
    const size_t qkv_bytes = (size_t)BATCH * NUM_HEADS * L_TOTAL * DK * 4;   // 5,087,232
    float* Qb  = (float*)(ws + o); o += qkv_bytes;
    float* Kb  = (float*)(ws + o); o += qkv_bytes;
    float* Vb  = (float*)(ws + o); o += qkv_bytes;
    float* Ctx = (float*)(ws + o); o += (size_t)BL * D_MODEL * 4;
    (void)ws_size; (void)in_sizes; (void)n_in; (void)out_size;

    mask_prep_kernel<<<(NUM_NODES * NUM_NODES + 255) / 256, 256, 0, stream>>>(tmask, smask, msmT);
    qkv_proj_kernel<<<BL / 16, 128, 0, stream>>>(x, Wq, bq, Wk, bk, Wv, bv, Qb, Kb, Vb);
    attn_kernel<<<dim3((L_TOTAL + 255) / 256, BATCH * NUM_HEADS), 256, 0, stream>>>(Qb, Kb, Vb, msmT, Ctx);
    out_proj_kernel<<<BL / 16, 128, 0, stream>>>(Ctx, Wo, bo, out);
}

// Round 5
// 271.399 us; speedup vs baseline: 2.3554x; 2.3554x over previous
//
#include <hip/hip_runtime.h>
#include <math.h>

#define D_MODEL   128
#define NUM_HEADS 8
#define DK        16
#define NUM_NODES 207
#define SEQ_LEN   12
#define BATCH     4
#define L_TOTAL   (SEQ_LEN * NUM_NODES)   // 2484
#define L_PAD     2496                    // 39*64, 78*32
#define BL        (BATCH * L_TOTAL)       // 9936

typedef short v4s __attribute__((ext_vector_type(4)));
typedef float v4f __attribute__((ext_vector_type(4)));

// Device pass: real MFMA builtin. Host pass: inert stub (parsed, never executed).
#if defined(__HIP_DEVICE_COMPILE__)
#define MFMA16(a, b, c) __builtin_amdgcn_mfma_f32_16x16x16bf16_1k(a, b, c, 0, 0, 0)
#else
#define MFMA16(a, b, c) (c)
#endif
#define EXP2F(x) exp2f(x)

// float -> bf16 (round to nearest even), pure bit ops (finite inputs only)
static __device__ __forceinline__ unsigned short f2bf(float f) {
    unsigned u = __builtin_bit_cast(unsigned, f);
    unsigned rnd = 0x7fffu + ((u >> 16) & 1u);
    return (unsigned short)((u + rnd) >> 16);
}
static __device__ __forceinline__ unsigned pk2bf(float a, float b) {
    return (unsigned)f2bf(a) | ((unsigned)f2bf(b) << 16);
}

// msmQ[nq][k] = 0.25 * log2(e) * sigmoid(tm) * sigmoid(sm[nq][k % 207]), k in [0, L_PAD)
__global__ void mask_prep_kernel(const float* __restrict__ tmask,
                                 const float* __restrict__ smask,
                                 float* __restrict__ msmQ) {
    int idx = blockIdx.x * 256 + threadIdx.x;
    if (idx >= NUM_NODES * L_PAD) return;
    int nq = idx / L_PAD;
    int k  = idx - nq * L_PAD;
    int nk = k % NUM_NODES;
    float tm = 1.0f / (1.0f + __expf(-tmask[0]));
    float sm = 1.0f / (1.0f + __expf(-smask[nq * NUM_NODES + nk]));
    msmQ[idx] = 0.25f * 1.4426950408889634f * tm * sm;
}

// QKV projection, fp32 compute -> bf16 stores.
// Qb,Kb: [bh][l_pad][16] bf16;  VbT: [bh][d=16][l_pad] bf16.
// Pad rows get x=0 -> bias only (finite, deterministic; masked in attention).
__global__ __launch_bounds__(128) void qkv_proj_kernel(
    const float* __restrict__ x,
    const float* __restrict__ Wq, const float* __restrict__ bq,
    const float* __restrict__ Wk, const float* __restrict__ bk,
    const float* __restrict__ Wv, const float* __restrict__ bv,
    short* __restrict__ Qb, short* __restrict__ Kb, short* __restrict__ VbT)
{
    __shared__ float xs[16][D_MODEL];
    const int t = threadIdx.x;
    const int row0 = blockIdx.x * 16;
    const int b  = row0 / L_PAD;
    const int l0 = row0 - b * L_PAD;
    #pragma unroll
    for (int r = 0; r < 16; ++r) {
        int l = l0 + r;
        xs[r][t] = (l < L_TOTAL) ? x[((size_t)b * L_TOTAL + l) * D_MODEL + t] : 0.f;
    }
    __syncthreads();

    float aq[16], ak[16], av[16];
    #pragma unroll
    for (int r = 0; r < 16; ++r) { aq[r] = 0.f; ak[r] = 0.f; av[r] = 0.f; }

    for (int i = 0; i < D_MODEL; ++i) {
        float wq = Wq[i * D_MODEL + t];
        float wk = Wk[i * D_MODEL + t];
        float wv = Wv[i * D_MODEL + t];
        #pragma unroll
        for (int r = 0; r < 16; ++r) {
            float xv = xs[r][i];
            aq[r] += xv * wq;
            ak[r] += xv * wk;
            av[r] += xv * wv;
        }
    }

    const float bqv = bq[t], bkv = bk[t], bvv = bv[t];
    const int h = t >> 4, d = t & 15;
    const int bh = b * NUM_HEADS + h;

    #pragma unroll
    for (int r = 0; r < 16; ++r) {
        size_t o = ((size_t)bh * L_PAD + (l0 + r)) * DK + d;
        Qb[o] = (short)f2bf(aq[r] + bqv);
        Kb[o] = (short)f2bf(ak[r] + bkv);
    }
    // V transposed, pairs packed into dword stores
    {
        short* vp = VbT + ((size_t)bh * DK + d) * L_PAD + l0;
        unsigned* vp4 = (unsigned*)vp;
        #pragma unroll
        for (int j = 0; j < 8; ++j)
            vp4[j] = pk2bf(av[2 * j] + bvv, av[2 * j + 1] + bvv);
    }
}

// MFMA attention: block = 4 waves, each wave owns 16 queries of one (b,h).
// Swapped QK^T (S^T = K*Q^T) so the S-frag feeds PV's A-operand in place.
// No LDS, no barriers, no online max (scores bounded: |dot*msm| < ~4).
__global__ __launch_bounds__(256) void attn_mfma_kernel(
    const short* __restrict__ Qb, const short* __restrict__ Kb,
    const short* __restrict__ VbT, const float* __restrict__ msmQ,
    float* __restrict__ Ctx)
{
    const int tid = threadIdx.x;
    const int l = tid & 63, w = tid >> 6;
    const int r = l & 15, g = l >> 4;
    const int bh = blockIdx.y, b = bh >> 3, h = bh & 7;
    const int q0w = blockIdx.x * 64 + w * 16;

    const short* Kp = Kb + (size_t)bh * L_PAD * DK;
    const short* Vp = VbT + ((size_t)bh * DK + r) * L_PAD;

    int qload = q0w + r;
    if (qload > L_TOTAL - 1) qload = L_TOTAL - 1;          // clamp pad queries
    const v4s qf = *(const v4s*)(Qb + ((size_t)bh * L_PAD + qload) * DK + 4 * g);
    const float* mp = msmQ + (size_t)((q0w + r) % NUM_NODES) * L_PAD;

    v4f ctx = {0.f, 0.f, 0.f, 0.f};
    float ss0 = 0.f, ss1 = 0.f, ss2 = 0.f, ss3 = 0.f;

#define SUBTILE(K_SUB, MASKED) do {                                            \
    v4s kf = *(const v4s*)(Kp + (size_t)((K_SUB) + r) * DK + 4 * g);           \
    v4s vf = *(const v4s*)(Vp + (K_SUB) + 4 * g);                              \
    v4f z = {0.f, 0.f, 0.f, 0.f};                                              \
    v4f sacc = MFMA16(kf, qf, z);                                              \
    float4 m4 = *(const float4*)(mp + (K_SUB) + 4 * g);                        \
    float p0 = EXP2F(sacc[0] * m4.x);                                          \
    float p1 = EXP2F(sacc[1] * m4.y);                                          \
    float p2 = EXP2F(sacc[2] * m4.z);                                          \
    float p3 = EXP2F(sacc[3] * m4.w);                                          \
    if (MASKED) {                                                              \
        int kb = (K_SUB) + 4 * g;                                              \
        if (kb + 0 >= L_TOTAL) p0 = 0.f;                                       \
        if (kb + 1 >= L_TOTAL) p1 = 0.f;                                       \
        if (kb + 2 >= L_TOTAL) p2 = 0.f;                                       \
        if (kb + 3 >= L_TOTAL) p3 = 0.f;                                       \
    }                                                                          \
    ss0 += p0; ss1 += p1; ss2 += p2; ss3 += p3;                                \
    unsigned plo = pk2bf(p0, p1);                                              \
    unsigned phi = pk2bf(p2, p3);                                              \
    v4s pf = __builtin_bit_cast(v4s, ((unsigned long long)phi << 32) | plo);   \
    ctx = MFMA16(pf, vf, ctx);                                                 \
} while (0)

    for (int kt = 0; kt < 2464; kt += 32) {
        SUBTILE(kt, false);
        SUBTILE(kt + 16, false);
    }
    SUBTILE(2464, false);   // keys 2464..2479 all valid
    SUBTILE(2480, true);    // keys 2480..2495: mask >= 2484
#undef SUBTILE

    // row sums: lane holds partials for q = r; combine the 4 lane-groups
    float s = (ss0 + ss1) + (ss2 + ss3);
    s += __shfl_xor(s, 16);
    s += __shfl_xor(s, 32);
    float inv = 1.0f / s;

    // ctx frag: lane holds (q = q0w + 4g + i, d = r)
    #pragma unroll
    for (int i = 0; i < 4; ++i) {
        int q = q0w + 4 * g + i;
        float iv = __shfl(inv, 4 * g + i);
        if (q < L_TOTAL)
            Ctx[((size_t)b * L_TOTAL + q) * D_MODEL + h * DK + r] = ctx[i] * iv;
    }
}

// Output projection: context (9936x128) @ Wo + bo -> out (fp32)
__global__ __launch_bounds__(128) void out_proj_kernel(
    const float* __restrict__ ctxin,
    const float* __restrict__ Wo, const float* __restrict__ bo,
    float* __restrict__ out)
{
    __shared__ float xs[16][D_MODEL];
    const int t = threadIdx.x;
    const int row0 = blockIdx.x * 16;
    #pragma unroll
    for (int r = 0; r < 16; ++r)
        xs[r][t] = ctxin[(size_t)(row0 + r) * D_MODEL + t];
    __syncthreads();

    float acc[16];
    #pragma unroll
    for (int r = 0; r < 16; ++r) acc[r] = 0.f;

    for (int i = 0; i < D_MODEL; ++i) {
        float wv = Wo[i * D_MODEL + t];
        #pragma unroll
        for (int r = 0; r < 16; ++r) acc[r] += xs[r][i] * wv;
    }

    float bv = bo[t];
    #pragma unroll
    for (int r = 0; r < 16; ++r)
        out[(size_t)(row0 + r) * D_MODEL + t] = acc[r] + bv;
}

extern "C" void kernel_launch(void* const* d_in, const int* in_sizes, int n_in,
                              void* d_out, int out_size, void* d_ws, size_t ws_size,
                              hipStream_t stream) {
    const float* x     = (const float*)d_in[0];
    const float* Wq    = (const float*)d_in[1];
    const float* bq    = (const float*)d_in[2];
    const float* Wk    = (const float*)d_in[3];
    const float* bk    = (const float*)d_in[4];
    const float* Wv    = (const float*)d_in[5];
    const float* bv    = (const float*)d_in[6];
    const float* Wo    = (const float*)d_in[7];
    const float* bo    = (const float*)d_in[8];
    const float* tmask = (const float*)d_in[9];
    const float* smask = (const float*)d_in[10];
    float* out = (float*)d_out;

    // workspace layout (~14.8 MB)
    char* ws = (char*)d_ws;
    size_t o = 0;
    float* msmQ = (float*)(ws + o); o += (size_t)NUM_NODES * L_PAD * 4;          // 2,066,688
    const size_t qk_bytes = (size_t)BATCH * NUM_HEADS * L_PAD * DK * 2;          // 2,555,904
    short* Qb  = (short*)(ws + o); o += qk_bytes;
    short* Kb  = (short*)(ws + o); o += qk_bytes;
    short* VbT = (short*)(ws + o); o += qk_bytes;
    float* Ctx = (float*)(ws + o); o += (size_t)BL * D_MODEL * 4;                // 5,087,232
    (void)ws_size; (void)in_sizes; (void)n_in; (void)out_size;

    mask_prep_kernel<<<(NUM_NODES * L_PAD + 255) / 256, 256, 0, stream>>>(tmask, smask, msmQ);
    qkv_proj_kernel<<<(BATCH * L_PAD) / 16, 128, 0, stream>>>(x, Wq, bq, Wk, bk, Wv, bv, Qb, Kb, VbT);
    attn_mfma_kernel<<<dim3(L_PAD / 64, BATCH * NUM_HEADS), 256, 0, stream>>>(Qb, Kb, VbT, msmQ, Ctx);
    out_proj_kernel<<<BL / 16, 128, 0, stream>>>(Ctx, Wo, bo, out);
}